// Round 4
// baseline (6304.455 us; speedup 1.0000x reference)
//
#include <hip/hip_runtime.h>

// LSTM: B=128, S=256, I=512, H=1024, O=512.
// bf16 MFMA persistent kernel, 128 wgs x 256 thr.
// Cross-block h exchange is done ENTIRELY with relaxed agent-scope atomics
// (global_load/store ... sc1: bypass non-coherent L1/L2, coherent at the
// fabric/MALL point). NO acquire/release fences anywhere in the step loop --
// fence(agent) on gfx950 lowers to whole-L2 buffer_inv/buffer_wbl2 (~10us
// each, and the inv forces full L2 refill every step: that was the 24us/step
// of round 3). Producer ordering = s_waitcnt vmcnt(0) (asm) before the
// arrive flag store. Weights/x stay on the cached path and remain L2-resident
// since L2 is never invalidated.
// Grid sync = distributed-slot barrier (block j stores its step count to its
// own slot; waiters poll with relaxed atomic loads). Deadlock-free: 128
// blocks < 256 CUs, all co-resident.
// Each wg owns 8 hidden units x 4 gates (32 gate-columns); Wh slice
// (32x1024 bf16 = 64 KiB) lives in LDS for all 256 steps, K-MAJOR layout
// (slot = kg*32 + n), conflict-free. Cell state c stays in VGPRs. x-part
// GEMM (no h dependence) runs BEFORE the barrier wait each step.

#define B_ 128
#define S_ 256
#define I_ 512
#define H_ 1024
#define O_ 512

typedef unsigned short u16;
typedef unsigned int u32;
typedef unsigned long long u64;

typedef short v8s __attribute__((ext_vector_type(8)));   // 8 x bf16 (4 VGPR)
typedef float v16f __attribute__((ext_vector_type(16)));
typedef float v4f __attribute__((ext_vector_type(4)));

struct P2 { u64 lo, hi; };

__device__ __forceinline__ u16 f2bf(float f) {
  u32 u = __float_as_uint(f);
  u32 r = (u + 0x7fffu + ((u >> 16) & 1u)) >> 16;   // RNE
  return (u16)r;
}
__device__ __forceinline__ u32 pack2(float a, float b) {
  return (u32)f2bf(a) | ((u32)f2bf(b) << 16);
}
__device__ __forceinline__ uint4 cvt8(const float* __restrict__ s) {
  float4 f0 = ((const float4*)s)[0];
  float4 f1 = ((const float4*)s)[1];
  uint4 o;
  o.x = pack2(f0.x, f0.y); o.y = pack2(f0.z, f0.w);
  o.z = pack2(f1.x, f1.y); o.w = pack2(f1.z, f1.w);
  return o;
}

// 16-byte load via two relaxed agent-scope atomic u64 loads (sc1: coherent
// at fabric, no cache-maintenance side effects).
__device__ __forceinline__ v8s ld_h16(const u16* p) {
  P2 q;
  q.lo = __hip_atomic_load((const u64*)p, __ATOMIC_RELAXED, __HIP_MEMORY_SCOPE_AGENT);
  q.hi = __hip_atomic_load((const u64*)p + 1, __ATOMIC_RELAXED, __HIP_MEMORY_SCOPE_AGENT);
  return __builtin_bit_cast(v8s, q);
}

// ---------------------------------------------------------------- prep ----
__global__ void lstm_prep(
    const float* __restrict__ x,
    const float* __restrict__ Whf, const float* __restrict__ Whi,
    const float* __restrict__ Whg, const float* __restrict__ Who,
    const float* __restrict__ Wxf, const float* __restrict__ Wxi,
    const float* __restrict__ Wxg, const float* __restrict__ Wxo,
    const float* __restrict__ bfp, const float* __restrict__ bip,
    const float* __restrict__ bgp, const float* __restrict__ bop,
    const float* __restrict__ Why,
    u16* __restrict__ xt, u16* __restrict__ Wc, float* __restrict__ bc,
    u16* __restrict__ WhyT, u16* __restrict__ hbuf, u32* __restrict__ barrier)
{
  const int gid = blockIdx.x * blockDim.x + threadIdx.x;
  const int gsz = gridDim.x * blockDim.x;

  if (gid < 256) barrier[gid] = 0u;   // zero barrier slots (ws is poisoned)

  // xt[t][b][i] <- x[b][t][i]  (bf16, time-major)
  for (int v = gid; v < (S_ * B_ * I_ / 8); v += gsz) {
    int flat = v * 8;
    int t = flat / (B_ * I_);
    int r = flat - t * (B_ * I_);
    int b = r / I_;
    int i = r - b * I_;
    const float* s = x + (size_t)b * (S_ * I_) + (size_t)t * I_ + i;
    *(uint4*)(xt + flat) = cvt8(s);
  }

  // Wc[n][k]: n = (unit_block<<5) + u_local*4 + gate; k<1024 -> Wh, else Wx
  for (int v = gid; v < (4096 * 1536 / 8); v += gsz) {
    int n = v / 192;
    int k = (v - n * 192) * 8;
    int unit = ((n >> 5) << 3) + ((n >> 2) & 7);
    int g = n & 3;
    const float* Whp = (g == 0) ? Whf : (g == 1) ? Whi : (g == 2) ? Whg : Who;
    const float* Wxp = (g == 0) ? Wxf : (g == 1) ? Wxi : (g == 2) ? Wxg : Wxo;
    const float* s = (k < 1024) ? (Whp + (size_t)unit * 1024 + k)
                                : (Wxp + (size_t)unit * 512 + (k - 1024));
    *(uint4*)(Wc + (size_t)n * 1536 + k) = cvt8(s);
  }

  // bias, gate-interleaved
  for (int n = gid; n < 4096; n += gsz) {
    int unit = ((n >> 5) << 3) + ((n >> 2) & 7);
    int g = n & 3;
    const float* bp = (g == 0) ? bfp : (g == 1) ? bip : (g == 2) ? bgp : bop;
    bc[n] = bp[unit];
  }

  // Why -> bf16 (row-major [o][k])
  for (int v = gid; v < (O_ * H_ / 8); v += gsz) {
    int flat = v * 8;
    *(uint4*)(WhyT + flat) = cvt8(Why + flat);
  }

  // zero both h ping-pong buffers
  for (int v = gid; v < (2 * B_ * H_ / 8); v += gsz) {
    uint4 z; z.x = 0; z.y = 0; z.z = 0; z.w = 0;
    *(uint4*)(hbuf + v * 8) = z;
  }
}

// ------------------------------------------------------ persistent LSTM ----
__global__ __launch_bounds__(256, 1) void lstm_seq(
    const u16* __restrict__ xt, const u16* __restrict__ Wc,
    const float* __restrict__ bc, u16* __restrict__ hbuf,
    const u16* __restrict__ WhyT, const float* __restrict__ WhyB,
    float* __restrict__ out, u32* __restrict__ barrier)
{
  // 64 KiB, K-MAJOR: slot(kg, n) = kg*32 + n  -> wave b128 reads stride-1,
  // conflict-free.
  __shared__ uint4 WhLds[4096];

  const int tid  = threadIdx.x;
  const int lane = tid & 63;
  const int w    = tid >> 6;     // wave 0..3, owns batch rows 32w..32w+31
  const int wg   = blockIdx.x;   // 0..127, owns hidden units wg*8..wg*8+7

  for (int s = tid; s < 4096; s += 256) {
    int kg = s >> 5;
    int n  = s & 31;
    WhLds[s] = *(const uint4*)(Wc + ((size_t)(wg * 32 + n)) * 1536 + (size_t)kg * 8);
  }
  __syncthreads();

  const int colN  = lane & 31;          // B n-index / C col (32x32 mfma)
  const int kgsel = lane >> 5;
  const int kg8   = kgsel << 3;
  const int rowA  = (w << 5) + colN;    // A m-index
  const int colG  = (wg << 5) + colN;   // global gate-col
  const int unit  = (wg << 3) + (colN >> 2);
  const int gate  = colN & 3;           // 0=f 1=i 2=g 3=o
  const float bias = bc[colG];

  float c[16];
#pragma unroll
  for (int i = 0; i < 16; ++i) c[i] = 0.f;

#pragma unroll 1
  for (int t = 0; t < S_; ++t) {
    const u16* hb = hbuf + (size_t)(t & 1) * (B_ * H_);
    u16* hn = hbuf + (size_t)((t & 1) ^ 1) * (B_ * H_);
    const u16* xb = xt + (size_t)t * (B_ * I_);

    v16f acc0, acc1;   // two chains so MFMA latency pipelines at 1 wave/SIMD
#pragma unroll
    for (int i = 0; i < 16; ++i) { acc0[i] = 0.f; acc1[i] = 0.f; }

    v8s abuf[2][8], bbuf[2][8];

    auto ldx = [&](int kc, v8s& a, v8s& b) {   // kc in [0,32): x-part K chunk
      a = *(const v8s*)(xb + (size_t)rowA * I_ + kc * 16 + kg8);
      b = *(const v8s*)(Wc + (size_t)colG * 1536 + 1024 + kc * 16 + kg8);
    };
    auto ldh = [&](int kc, v8s& a, v8s& b) {   // kc in [0,64): h-part K chunk
      a = ld_h16(hb + (size_t)rowA * H_ + kc * 16 + kg8);   // sc1 atomic pair
      b = __builtin_bit_cast(v8s, WhLds[((kc * 2 + kgsel) << 5) + colN]);
    };

    // ---- x-part: no dependence on h_{t-1}; runs before the barrier wait ----
#pragma unroll
    for (int j = 0; j < 8; ++j) ldx(j, abuf[0][j], bbuf[0][j]);
#pragma unroll
    for (int g = 0; g < 4; ++g) {
      const int cur = g & 1;
      if (g < 3) {
#pragma unroll
        for (int j = 0; j < 8; ++j)
          ldx((g + 1) * 8 + j, abuf[cur ^ 1][j], bbuf[cur ^ 1][j]);
      }
#pragma unroll
      for (int j = 0; j < 8; j += 2) {
        acc0 = __builtin_amdgcn_mfma_f32_32x32x16_bf16(abuf[cur][j], bbuf[cur][j], acc0, 0, 0, 0);
        acc1 = __builtin_amdgcn_mfma_f32_32x32x16_bf16(abuf[cur][j + 1], bbuf[cur][j + 1], acc1, 0, 0, 0);
      }
    }

    // ---- wait: h_{t-1} ready when every block's slot >= t. Relaxed polls,
    // NO fence: h itself travels via sc1 atomics, coherent at fabric. ----
    if (t > 0) {
      if (tid < 128) {
        u32 spins = 0;
        while (__hip_atomic_load(&barrier[tid], __ATOMIC_RELAXED,
                                 __HIP_MEMORY_SCOPE_AGENT) < (u32)t) {
          __builtin_amdgcn_s_sleep(1);
          if (++spins > (1u << 22)) break;   // safety valve vs. hang
        }
      }
      __syncthreads();
    }

    // ---- h-part ----
#pragma unroll
    for (int j = 0; j < 8; ++j) ldh(j, abuf[0][j], bbuf[0][j]);
#pragma unroll
    for (int g = 0; g < 8; ++g) {
      const int cur = g & 1;
      if (g < 7) {
#pragma unroll
        for (int j = 0; j < 8; ++j)
          ldh((g + 1) * 8 + j, abuf[cur ^ 1][j], bbuf[cur ^ 1][j]);
      }
#pragma unroll
      for (int j = 0; j < 8; j += 2) {
        acc0 = __builtin_amdgcn_mfma_f32_32x32x16_bf16(abuf[cur][j], bbuf[cur][j], acc0, 0, 0, 0);
        acc1 = __builtin_amdgcn_mfma_f32_32x32x16_bf16(abuf[cur][j + 1], bbuf[cur][j + 1], acc1, 0, 0, 0);
      }
    }

    // ---- gates / state update / h write (sc1 atomic write-through) ----
    const bool lastT = (t == S_ - 1);
#pragma unroll
    for (int r = 0; r < 16; ++r) {
      float pre = acc0[r] + acc1[r] + bias;
      // gate 2 -> tanh (overflow-safe), others -> sigmoid
      float e = __expf((gate == 2) ? (2.f * pre) : (-pre));
      float act = (gate == 2) ? (1.f - 2.f / (e + 1.f)) : (1.f / (1.f + e));
      int qb = lane & ~3;   // quad holds f,i,g,o of one (row,unit)
      float F = __shfl(act, qb + 0, 64);
      float I = __shfl(act, qb + 1, 64);
      float G = __shfl(act, qb + 2, 64);
      float O = __shfl(act, qb + 3, 64);
      float cn = fmaf(F, c[r], I * G);
      c[r] = cn;
      float e2 = __expf(2.f * cn);
      float hv = O * (1.f - 2.f / (e2 + 1.f));
      if (gate == 0) {
        int row = (w << 5) + (r & 3) + ((r >> 2) << 3) + (kgsel << 2);
        __hip_atomic_store(hn + (size_t)row * H_ + unit, f2bf(hv),
                           __ATOMIC_RELAXED, __HIP_MEMORY_SCOPE_AGENT);
        if (lastT) {
          out[65536 + row * H_ + unit] = hv;    // h output (fp32)
          out[196608 + row * H_ + unit] = cn;   // c output (fp32)
        }
      }
    }

    // ---- arrive: per-wave drain of h store-acks (they are write-through
    // sc1 stores, so vmcnt(0) == globally visible), then block barrier, then
    // one relaxed flag store. No wbl2, no inv. ----
    asm volatile("s_waitcnt vmcnt(0)" ::: "memory");
    __syncthreads();
    if (tid == 0)
      __hip_atomic_store(&barrier[wg], (u32)(t + 1), __ATOMIC_RELAXED,
                         __HIP_MEMORY_SCOPE_AGENT);
  }

  // ---- wait for ALL blocks' final h, then out = h_final @ Why^T + b ----
  if (tid < 128) {
    u32 spins = 0;
    while (__hip_atomic_load(&barrier[tid], __ATOMIC_RELAXED,
                             __HIP_MEMORY_SCOPE_AGENT) < (u32)S_) {
      __builtin_amdgcn_s_sleep(1);
      if (++spins > (1u << 22)) break;
    }
  }
  __syncthreads();

  // final h is in buffer 0 (S_=256 is even); read via the same sc1 path
  if (wg < 32) {
    const u16* hf = hbuf;
    const int l15 = lane & 15;
    const int l4 = lane >> 4;
    const int colO = (wg << 4) + l15;
    v4f o0, o1;
#pragma unroll
    for (int i = 0; i < 4; ++i) { o0[i] = 0.f; o1[i] = 0.f; }
#pragma unroll 4
    for (int kc = 0; kc < 32; ++kc) {
      v8s bfrag = *(const v8s*)(WhyT + (size_t)colO * H_ + kc * 32 + (l4 << 3));
      v8s a0 = ld_h16(hf + (size_t)((w << 5) + l15) * H_ + kc * 32 + (l4 << 3));
      v8s a1 = ld_h16(hf + (size_t)((w << 5) + 16 + l15) * H_ + kc * 32 + (l4 << 3));
      o0 = __builtin_amdgcn_mfma_f32_16x16x32_bf16(a0, bfrag, o0, 0, 0, 0);
      o1 = __builtin_amdgcn_mfma_f32_16x16x32_bf16(a1, bfrag, o1, 0, 0, 0);
    }
    float bO = WhyB[colO];
#pragma unroll
    for (int r = 0; r < 4; ++r) {
      int row = (w << 5) + (l4 << 2) + r;
      out[row * O_ + colO] = o0[r] + bO;
      out[(row + 16) * O_ + colO] = o1[r] + bO;
    }
  }
}

// ------------------------------------------------------------- launch ----
extern "C" void kernel_launch(void* const* d_in, const int* in_sizes, int n_in,
                              void* d_out, int out_size, void* d_ws, size_t ws_size,
                              hipStream_t stream) {
  const float* x    = (const float*)d_in[0];
  const float* Wxf  = (const float*)d_in[1];
  const float* bf_  = (const float*)d_in[2];
  const float* Whf  = (const float*)d_in[3];
  const float* Wxi  = (const float*)d_in[4];
  const float* bi_  = (const float*)d_in[5];
  const float* Whi  = (const float*)d_in[6];
  const float* Wxg  = (const float*)d_in[7];
  const float* bg_  = (const float*)d_in[8];
  const float* Whg  = (const float*)d_in[9];
  const float* Wxo  = (const float*)d_in[10];
  const float* bo_  = (const float*)d_in[11];
  const float* Who  = (const float*)d_in[12];
  const float* Why  = (const float*)d_in[13];
  const float* Whyb = (const float*)d_in[14];

  char* ws = (char*)d_ws;
  u16*   xtp  = (u16*)(ws);                    // 33,554,432 B
  u16*   Wcp  = (u16*)(ws + 33554432);         // 12,582,912 B
  float* bcp  = (float*)(ws + 46137344);       //     16,384 B
  u16*   WhyT = (u16*)(ws + 46153728);         //  1,048,576 B
  u16*   hbuf = (u16*)(ws + 47202304);         //    524,288 B
  u32*   barp = (u32*)(ws + 47726592);         //      1,024 B  (total ~47.7 MB)
  float* outp = (float*)d_out;

  lstm_prep<<<dim3(1024), dim3(256), 0, stream>>>(
      x, Whf, Whi, Whg, Who, Wxf, Wxi, Wxg, Wxo,
      bf_, bi_, bg_, bo_, Why, xtp, Wcp, bcp, WhyT, hbuf, barp);

  lstm_seq<<<dim3(128), dim3(256), 0, stream>>>(
      xtp, Wcp, bcp, hbuf, WhyT, Whyb, outp, barp);
}

// Round 5
// 2896.087 us; speedup vs baseline: 2.1769x; 2.1769x over previous
//
#include <hip/hip_runtime.h>

// LSTM: B=128, S=256, I=512, H=1024, O=512.
// bf16 MFMA persistent kernel, 128 wgs x 256 thr.
// R5: kill per-lane gathers. 2D split: block = (batch-half rh, col-group cg):
// 64 rows x 64 gate-cols. All global operands staged through LDS with
// COALESCED loads (16B/lane, consecutive lanes -> consecutive addresses):
//   K-chunks of 128: chunks 0..3 = x-part (xt + Wc[k>=1024], cached),
//   chunks 4..11 = h-part (hbuf via relaxed agent atomics = UC/fabric-coherent,
//   Wc[k<1024] cached). LDS = 4 x 16 KB double buffers, fragment-order layout
//   w/ XOR swizzle: frag reads are contiguous 1 KB per wave (conflict-free).
// h writes: LDS gather -> 16B UC stores (2 per row) instead of scalar u16s.
// Sync: two independent 64-block half-barriers (slot per block, relaxed
// atomics, no fences anywhere -- h travels UC; producers drain with
// s_waitcnt vmcnt(0) before flag). Deadlock-free: 128 blocks < 256 CUs.

#define B_ 128
#define S_ 256
#define I_ 512
#define H_ 1024
#define O_ 512

typedef unsigned short u16;
typedef unsigned int u32;
typedef unsigned long long u64;

typedef short v8s __attribute__((ext_vector_type(8)));   // 8 x bf16 (4 VGPR)
typedef float v16f __attribute__((ext_vector_type(16)));
typedef float v4f __attribute__((ext_vector_type(4)));

__device__ __forceinline__ u16 f2bf(float f) {
  u32 u = __float_as_uint(f);
  u32 r = (u + 0x7fffu + ((u >> 16) & 1u)) >> 16;   // RNE
  return (u16)r;
}
__device__ __forceinline__ u32 pack2(float a, float b) {
  return (u32)f2bf(a) | ((u32)f2bf(b) << 16);
}
__device__ __forceinline__ uint4 cvt8(const float* __restrict__ s) {
  float4 f0 = ((const float4*)s)[0];
  float4 f1 = ((const float4*)s)[1];
  uint4 o;
  o.x = pack2(f0.x, f0.y); o.y = pack2(f0.z, f0.w);
  o.z = pack2(f1.x, f1.y); o.w = pack2(f1.z, f1.w);
  return o;
}

// 16B load/store via relaxed agent-scope atomic u64 pairs (sc1: bypass the
// non-coherent L1/L2, coherent at fabric; NO cache-maintenance side effects).
__device__ __forceinline__ uint4 uc_ld16(const u16* p) {
  u64 lo = __hip_atomic_load((const u64*)p, __ATOMIC_RELAXED, __HIP_MEMORY_SCOPE_AGENT);
  u64 hi = __hip_atomic_load((const u64*)p + 1, __ATOMIC_RELAXED, __HIP_MEMORY_SCOPE_AGENT);
  uint4 v; v.x = (u32)lo; v.y = (u32)(lo >> 32); v.z = (u32)hi; v.w = (u32)(hi >> 32);
  return v;
}
__device__ __forceinline__ void uc_st16(u16* p, uint4 v) {
  u64 lo = (u64)v.x | ((u64)v.y << 32);
  u64 hi = (u64)v.z | ((u64)v.w << 32);
  __hip_atomic_store((u64*)p, lo, __ATOMIC_RELAXED, __HIP_MEMORY_SCOPE_AGENT);
  __hip_atomic_store((u64*)p + 1, hi, __ATOMIC_RELAXED, __HIP_MEMORY_SCOPE_AGENT);
}
__device__ __forceinline__ v8s ld_h16(const u16* p) {
  return __builtin_bit_cast(v8s, uc_ld16(p));
}

// ---------------------------------------------------------------- prep ----
__global__ void lstm_prep(
    const float* __restrict__ x,
    const float* __restrict__ Whf, const float* __restrict__ Whi,
    const float* __restrict__ Whg, const float* __restrict__ Who,
    const float* __restrict__ Wxf, const float* __restrict__ Wxi,
    const float* __restrict__ Wxg, const float* __restrict__ Wxo,
    const float* __restrict__ bfp, const float* __restrict__ bip,
    const float* __restrict__ bgp, const float* __restrict__ bop,
    const float* __restrict__ Why,
    u16* __restrict__ xt, u16* __restrict__ Wc, float* __restrict__ bc,
    u16* __restrict__ WhyT, u16* __restrict__ hbuf, u32* __restrict__ barrier)
{
  const int gid = blockIdx.x * blockDim.x + threadIdx.x;
  const int gsz = gridDim.x * blockDim.x;

  if (gid < 256) barrier[gid] = 0u;   // zero barrier slots (ws is poisoned)

  // xt[t][b][i] <- x[b][t][i]  (bf16, time-major)
  for (int v = gid; v < (S_ * B_ * I_ / 8); v += gsz) {
    int flat = v * 8;
    int t = flat / (B_ * I_);
    int r = flat - t * (B_ * I_);
    int b = r / I_;
    int i = r - b * I_;
    const float* s = x + (size_t)b * (S_ * I_) + (size_t)t * I_ + i;
    *(uint4*)(xt + flat) = cvt8(s);
  }

  // Wc[n][k]: n = (unit_block<<5) + u_local*4 + gate; k<1024 -> Wh, else Wx
  for (int v = gid; v < (4096 * 1536 / 8); v += gsz) {
    int n = v / 192;
    int k = (v - n * 192) * 8;
    int unit = ((n >> 5) << 3) + ((n >> 2) & 7);
    int g = n & 3;
    const float* Whp = (g == 0) ? Whf : (g == 1) ? Whi : (g == 2) ? Whg : Who;
    const float* Wxp = (g == 0) ? Wxf : (g == 1) ? Wxi : (g == 2) ? Wxg : Wxo;
    const float* s = (k < 1024) ? (Whp + (size_t)unit * 1024 + k)
                                : (Wxp + (size_t)unit * 512 + (k - 1024));
    *(uint4*)(Wc + (size_t)n * 1536 + k) = cvt8(s);
  }

  // bias, gate-interleaved
  for (int n = gid; n < 4096; n += gsz) {
    int unit = ((n >> 5) << 3) + ((n >> 2) & 7);
    int g = n & 3;
    const float* bp = (g == 0) ? bfp : (g == 1) ? bip : (g == 2) ? bgp : bop;
    bc[n] = bp[unit];
  }

  // Why -> bf16 (row-major [o][k])
  for (int v = gid; v < (O_ * H_ / 8); v += gsz) {
    int flat = v * 8;
    *(uint4*)(WhyT + flat) = cvt8(Why + flat);
  }

  // zero both h ping-pong buffers
  for (int v = gid; v < (2 * B_ * H_ / 8); v += gsz) {
    uint4 z; z.x = 0; z.y = 0; z.z = 0; z.w = 0;
    *(uint4*)(hbuf + v * 8) = z;
  }
}

// ------------------------------------------------------ persistent LSTM ----
struct SetR { uint4 a[4]; uint4 b[4]; };

__global__ __launch_bounds__(256, 1) void lstm_seq(
    const u16* __restrict__ xt, const u16* __restrict__ Wc,
    const float* __restrict__ bc, u16* __restrict__ hbuf,
    const u16* __restrict__ WhyT, const float* __restrict__ WhyB,
    float* __restrict__ out, u32* __restrict__ barrier)
{
  // 4 x 16 KB double buffers, fragment-order + XOR swizzle:
  // idx16(r,c) = (c>>1)*128 + (r>>5)*64 + (c&1)*32 + ((r&31) ^ (c&7))
  // frag read at (kc, tile, kgsel): contiguous (permuted) 1 KB -> conflict-free.
  __shared__ uint4 SA[2][1024];
  __shared__ uint4 SB[2][1024];

  const int tid  = threadIdx.x;
  const int lane = tid & 63;
  const int w    = tid >> 6;        // wave 0..3
  const int rt   = w & 1;           // row-tile within 64-row half
  const int ct   = w >> 1;          // col-tile within 64-col group
  const int rh   = blockIdx.x & 1;  // batch half (rows rh*64 .. rh*64+63)
  const int cg   = blockIdx.x >> 1; // col group (gate-cols cg*64 .. +63)

  const int colN  = lane & 31;
  const int kgsel = lane >> 5;

  // staging constants: thread covers 4 16B-chunks; r = row/col 0..63, c = 0..15
  int rr[4], cc[4], li[4];
#pragma unroll
  for (int i = 0; i < 4; ++i) {
    int flat = i * 256 + tid;
    int r = flat >> 4, c = flat & 15;
    rr[i] = r; cc[i] = c * 8;
    li[i] = (c >> 1) * 128 + (r >> 5) * 64 + (c & 1) * 32 + ((r & 31) ^ (c & 7));
  }

  const u16* WcB = Wc + (size_t)(cg * 64) * 1536;   // this block's 64 cols
  const int colL = ct * 32 + colN;                  // col within group (0..63)
  const float bias = bc[cg * 64 + colL];
  const int gate = colN & 3;                        // 0=f 1=i 2=g 3=o
  const int unitL = ct * 8 + (colN >> 2);           // unit within group (0..15)

  float c[16];
#pragma unroll
  for (int i = 0; i < 16; ++i) c[i] = 0.f;

  v16f acc0, acc1;
  SetR s0, s1;

#pragma unroll 1
  for (int t = 0; t < S_; ++t) {
    const u16* hb = hbuf + (size_t)(t & 1) * (B_ * H_) + (size_t)rh * 64 * H_;
    u16* hn = hbuf + (size_t)((t & 1) ^ 1) * (B_ * H_) + (size_t)rh * 64 * H_;
    const u16* xb = xt + (size_t)t * (B_ * I_) + (size_t)rh * 64 * I_;

#pragma unroll
    for (int i = 0; i < 16; ++i) { acc0[i] = 0.f; acc1[i] = 0.f; }

    // coalesced staging loads (16B/lane, consecutive lanes -> consecutive addr)
    auto ldX = [&](SetR& s, int kb) {   // x chunk kb in 0..3
#pragma unroll
      for (int i = 0; i < 4; ++i) {
        s.a[i] = *(const uint4*)(xb + rr[i] * I_ + kb * 128 + cc[i]);
        s.b[i] = *(const uint4*)(WcB + (size_t)rr[i] * 1536 + 1024 + kb * 128 + cc[i]);
      }
    };
    auto ldH = [&](SetR& s, int kb) {   // h chunk kb in 0..7 (UC A loads)
#pragma unroll
      for (int i = 0; i < 4; ++i) {
        s.a[i] = uc_ld16(hb + rr[i] * H_ + kb * 128 + cc[i]);
        s.b[i] = *(const uint4*)(WcB + (size_t)rr[i] * 1536 + kb * 128 + cc[i]);
      }
    };
    auto wrS = [&](int half, SetR& s) {
#pragma unroll
      for (int i = 0; i < 4; ++i) { SA[half][li[i]] = s.a[i]; SB[half][li[i]] = s.b[i]; }
    };
    auto mmS = [&](int half) {
#pragma unroll
      for (int kc = 0; kc < 8; ++kc) {
        int xo = colN ^ ((kc * 2 + kgsel) & 7);
        v8s aF = __builtin_bit_cast(v8s, SA[half][kc * 128 + rt * 64 + kgsel * 32 + xo]);
        v8s bF = __builtin_bit_cast(v8s, SB[half][kc * 128 + ct * 64 + kgsel * 32 + xo]);
        if (kc & 1) acc1 = __builtin_amdgcn_mfma_f32_32x32x16_bf16(aF, bF, acc1, 0, 0, 0);
        else        acc0 = __builtin_amdgcn_mfma_f32_32x32x16_bf16(aF, bF, acc0, 0, 0, 0);
      }
    };

    // ---- x-phase (no h dependence): chunks 0..3, double-buffered ----
    ldX(s0, 0); ldX(s1, 1);
    wrS(0, s0);
    __syncthreads();
    wrS(1, s1); ldX(s0, 2); mmS(0); __syncthreads();
    wrS(0, s0); ldX(s1, 3); mmS(1); __syncthreads();
    wrS(1, s1);             mmS(0); __syncthreads();
                            mmS(1);

    // ---- half-barrier wait: h_{t-1} of this half ready ----
    if (t > 0) {
      if (tid < 64) {
        u32 spins = 0;
        while (__hip_atomic_load(&barrier[rh * 64 + lane], __ATOMIC_RELAXED,
                                 __HIP_MEMORY_SCOPE_AGENT) < (u32)t) {
          __builtin_amdgcn_s_sleep(2);
          if (++spins > (1u << 22)) break;   // safety valve vs. hang
        }
      }
    }
    __syncthreads();

    // ---- h-phase: chunks 0..7, double-buffered (A via UC atomics) ----
    ldH(s0, 0); ldH(s1, 1);
    wrS(0, s0);
    __syncthreads();
    wrS(1, s1); ldH(s0, 2); mmS(0); __syncthreads();
    wrS(0, s0); ldH(s1, 3); mmS(1); __syncthreads();
    wrS(1, s1); ldH(s0, 4); mmS(0); __syncthreads();
    wrS(0, s0); ldH(s1, 5); mmS(1); __syncthreads();
    wrS(1, s1); ldH(s0, 6); mmS(0); __syncthreads();
    wrS(0, s0); ldH(s1, 7); mmS(1); __syncthreads();
    wrS(1, s1);             mmS(0); __syncthreads();
                            mmS(1);

    // ---- gates / state update ----
    u16* hstage = (u16*)&SA[0][0];   // 2 KB scratch (SA[0] free: last read kb=6)
    const bool lastT = (t == S_ - 1);
#pragma unroll
    for (int r = 0; r < 16; ++r) {
      float pre = acc0[r] + acc1[r] + bias;
      // gate 2 -> tanh (overflow-safe), others -> sigmoid
      float e = __expf((gate == 2) ? (2.f * pre) : (-pre));
      float act = (gate == 2) ? (1.f - 2.f / (e + 1.f)) : (1.f / (1.f + e));
      int qb = lane & ~3;   // quad holds f,i,g,o of one (row,unit)
      float F = __shfl(act, qb + 0, 64);
      float I = __shfl(act, qb + 1, 64);
      float G = __shfl(act, qb + 2, 64);
      float O = __shfl(act, qb + 3, 64);
      float cn = fmaf(F, c[r], I * G);
      c[r] = cn;
      float e2 = __expf(2.f * cn);
      float hv = O * (1.f - 2.f / (e2 + 1.f));
      if (gate == 0) {
        int rowL = rt * 32 + (r & 3) + ((r >> 2) << 3) + (kgsel << 2);  // 0..63
        hstage[rowL * 16 + unitL] = f2bf(hv);
        if (lastT) {
          int grow = rh * 64 + rowL;
          int gunit = cg * 16 + unitL;
          out[65536 + grow * H_ + gunit] = hv;    // h output (fp32)
          out[196608 + grow * H_ + gunit] = cn;   // c output (fp32)
        }
      }
    }
    __syncthreads();

    // ---- coalesced h write: 2 x 16B UC stores per row ----
    if (tid < 128) {
      int r = tid >> 1, hf16 = tid & 1;
      uint4 v = *(const uint4*)(hstage + r * 16 + hf16 * 8);
      uc_st16(hn + (size_t)r * H_ + cg * 16 + hf16 * 8, v);
    }

    // ---- arrive: drain UC store acks, block barrier, flag own slot ----
    asm volatile("s_waitcnt vmcnt(0)" ::: "memory");
    __syncthreads();
    if (tid == 0)
      __hip_atomic_store(&barrier[rh * 64 + cg], (u32)(t + 1), __ATOMIC_RELAXED,
                         __HIP_MEMORY_SCOPE_AGENT);
  }

  // ---- full barrier (both halves), then out = h_final @ Why^T + b ----
  if (tid < 128) {
    u32 spins = 0;
    while (__hip_atomic_load(&barrier[tid], __ATOMIC_RELAXED,
                             __HIP_MEMORY_SCOPE_AGENT) < (u32)S_) {
      __builtin_amdgcn_s_sleep(2);
      if (++spins > (1u << 22)) break;
    }
  }
  __syncthreads();

  // final h is in buffer 0 (S_=256 even); read via UC path (one-time cost)
  if (blockIdx.x < 32) {
    const int wg = blockIdx.x;
    const u16* hf = hbuf;
    const int l15 = lane & 15;
    const int l4 = lane >> 4;
    const int colO = (wg << 4) + l15;
    v4f o0, o1;
#pragma unroll
    for (int i = 0; i < 4; ++i) { o0[i] = 0.f; o1[i] = 0.f; }
#pragma unroll 4
    for (int kc = 0; kc < 32; ++kc) {
      v8s bfrag = *(const v8s*)(WhyT + (size_t)colO * H_ + kc * 32 + (l4 << 3));
      v8s a0 = ld_h16(hf + (size_t)((w << 5) + l15) * H_ + kc * 32 + (l4 << 3));
      v8s a1 = ld_h16(hf + (size_t)((w << 5) + 16 + l15) * H_ + kc * 32 + (l4 << 3));
      o0 = __builtin_amdgcn_mfma_f32_16x16x32_bf16(a0, bfrag, o0, 0, 0, 0);
      o1 = __builtin_amdgcn_mfma_f32_16x16x32_bf16(a1, bfrag, o1, 0, 0, 0);
    }
    float bO = WhyB[colO];
#pragma unroll
    for (int r = 0; r < 4; ++r) {
      int row = (w << 5) + (l4 << 2) + r;
      out[row * O_ + colO] = o0[r] + bO;
      out[(row + 16) * O_ + colO] = o1[r] + bO;
    }
  }
}

// ------------------------------------------------------------- launch ----
extern "C" void kernel_launch(void* const* d_in, const int* in_sizes, int n_in,
                              void* d_out, int out_size, void* d_ws, size_t ws_size,
                              hipStream_t stream) {
  const float* x    = (const float*)d_in[0];
  const float* Wxf  = (const float*)d_in[1];
  const float* bf_  = (const float*)d_in[2];
  const float* Whf  = (const float*)d_in[3];
  const float* Wxi  = (const float*)d_in[4];
  const float* bi_  = (const float*)d_in[5];
  const float* Whi  = (const float*)d_in[6];
  const float* Wxg  = (const float*)d_in[7];
  const float* bg_  = (const float*)d_in[8];
  const float* Whg  = (const float*)d_in[9];
  const float* Wxo  = (const float*)d_in[10];
  const float* bo_  = (const float*)d_in[11];
  const float* Who  = (const float*)d_in[12];
  const float* Why  = (const float*)d_in[13];
  const float* Whyb = (const float*)d_in[14];

  char* ws = (char*)d_ws;
  u16*   xtp  = (u16*)(ws);                    // 33,554,432 B
  u16*   Wcp  = (u16*)(ws + 33554432);         // 12,582,912 B
  float* bcp  = (float*)(ws + 46137344);       //     16,384 B
  u16*   WhyT = (u16*)(ws + 46153728);         //  1,048,576 B
  u16*   hbuf = (u16*)(ws + 47202304);         //    524,288 B
  u32*   barp = (u32*)(ws + 47726592);         //      1,024 B  (total ~47.7 MB)
  float* outp = (float*)d_out;

  lstm_prep<<<dim3(1024), dim3(256), 0, stream>>>(
      x, Whf, Whi, Whg, Who, Wxf, Wxi, Wxg, Wxo,
      bf_, bi_, bg_, bo_, Why, xtp, Wcp, bcp, WhyT, hbuf, barp);

  lstm_seq<<<dim3(128), dim3(256), 0, stream>>>(
      xtp, Wcp, bcp, hbuf, WhyT, Whyb, outp, barp);
}